// Round 1
// baseline (415.815 us; speedup 1.0000x reference)
//
#include <hip/hip_runtime.h>

// Problem constants: B=2, S=2048, D=1024, H=16, HD=64
#define S_LEN 2048
#define NH 16
#define HD 64
#define DMODEL 1024

typedef __bf16 bf16x8 __attribute__((ext_vector_type(8)));
typedef float floatx4 __attribute__((ext_vector_type(4)));
typedef short short8 __attribute__((ext_vector_type(8)));

__device__ inline unsigned short f2bf(float f) {
    union { float f; unsigned u; } v; v.f = f;
    unsigned u = v.u;
    unsigned r = (u + 0x7FFFu + ((u >> 16) & 1u)) >> 16;  // RNE
    return (unsigned short)r;
}

// ---------------------------------------------------------------------------
// K1: qkv = x @ w_qkv^T + b_qkv, fused RoPE, scatter to q/k/v (B,H,S,HD) bf16
// NT GEMM: C[m,n] = sum_k x[m,k] * w[n,k].  M=4096, N=3072, K=1024.
// 64x64 tile / block (256 thr = 4 waves, wave w owns 16-row strip), BK=32.
// ---------------------------------------------------------------------------
__global__ __launch_bounds__(256) void qkv_rope_kernel(
    const float* __restrict__ x, const float* __restrict__ w,
    const float* __restrict__ bias, const float* __restrict__ freqs,
    unsigned short* __restrict__ qb, unsigned short* __restrict__ kb,
    unsigned short* __restrict__ vb)
{
    __shared__ __align__(16) unsigned short As[64 * 40];  // 64 x (32+8 pad)
    __shared__ __align__(16) unsigned short Bs[64 * 40];
    const int t = threadIdx.x;
    const int mbase = (blockIdx.x / 48) * 64;
    const int nbase = (blockIdx.x % 48) * 64;
    const int wv = t >> 6, lane = t & 63;
    const int quad = lane >> 4, l16 = lane & 15;

    floatx4 acc[4];
    for (int i = 0; i < 4; i++)
        for (int r = 0; r < 4; r++) acc[i][r] = 0.f;

    const int srow = t >> 2;        // 0..63
    const int sc8  = (t & 3) * 8;   // 0,8,16,24

    for (int k0 = 0; k0 < DMODEL; k0 += 32) {
        const float* ap = x + (size_t)(mbase + srow) * DMODEL + k0 + sc8;
        const float* bp = w + (size_t)(nbase + srow) * DMODEL + k0 + sc8;
        float4 a0 = *(const float4*)ap;
        float4 a1 = *(const float4*)(ap + 4);
        float4 b0 = *(const float4*)bp;
        float4 b1 = *(const float4*)(bp + 4);
        short8 av, bv;
        av[0]=(short)f2bf(a0.x); av[1]=(short)f2bf(a0.y); av[2]=(short)f2bf(a0.z); av[3]=(short)f2bf(a0.w);
        av[4]=(short)f2bf(a1.x); av[5]=(short)f2bf(a1.y); av[6]=(short)f2bf(a1.z); av[7]=(short)f2bf(a1.w);
        bv[0]=(short)f2bf(b0.x); bv[1]=(short)f2bf(b0.y); bv[2]=(short)f2bf(b0.z); bv[3]=(short)f2bf(b0.w);
        bv[4]=(short)f2bf(b1.x); bv[5]=(short)f2bf(b1.y); bv[6]=(short)f2bf(b1.z); bv[7]=(short)f2bf(b1.w);
        __syncthreads();                        // previous iter's LDS reads done
        *(short8*)&As[srow * 40 + sc8] = av;
        *(short8*)&Bs[srow * 40 + sc8] = bv;
        __syncthreads();                        // stores visible
        bf16x8 af = *(const bf16x8*)&As[(wv * 16 + l16) * 40 + quad * 8];
        for (int nt = 0; nt < 4; nt++) {
            bf16x8 bf = *(const bf16x8*)&Bs[(nt * 16 + l16) * 40 + quad * 8];
            acc[nt] = __builtin_amdgcn_mfma_f32_16x16x32_bf16(af, bf, acc[nt], 0, 0, 0);
        }
    }

    // Epilogue: bias + RoPE + scatter. C layout: col=lane&15, row=quad*4+reg.
    for (int nt = 0; nt < 4; nt++) {
        const int n = nbase + nt * 16 + l16;
        const int part = n >> 10;        // 0=q 1=k 2=v
        const int rem  = n & 1023;
        const int h    = rem >> 6;
        const int hd   = rem & 63;
        unsigned short* dst = (part == 0) ? qb : (part == 1) ? kb : vb;
        const float bvv = bias[n];
        for (int r = 0; r < 4; r++) {
            const int m = mbase + wv * 16 + quad * 4 + r;
            const int b = m >> 11;       // /S_LEN
            const int s = m & 2047;
            float val = acc[nt][r] + bvv;
            float other = __shfl_xor(val, 1, 64);  // RoPE pair = adjacent col = adjacent lane
            float outv;
            if (part == 2) {
                outv = val;
            } else {
                const int i = hd >> 1;
                const float f = freqs[s * 32 + i];
                const float c = cosf(f), sn = sinf(f);
                if ((hd & 1) == 0) outv = val * c - other * sn;   // t0*c - t1*s
                else               outv = other * sn + val * c;   // t0*s + t1*c
            }
            dst[(((size_t)b * NH + h) * S_LEN + s) * HD + hd] = f2bf(outv);
        }
    }
}

// ---------------------------------------------------------------------------
// K2: causal flash attention. Block = 256 thr (4 waves), 64 q-rows per block,
// wave owns 16 q-rows. K-tiles of 32 keys. Grid = B*H*(S/64) = 1024.
// ---------------------------------------------------------------------------
__global__ __launch_bounds__(256) void attn_kernel(
    const unsigned short* __restrict__ qb, const unsigned short* __restrict__ kb,
    const unsigned short* __restrict__ vb, unsigned short* __restrict__ ao)
{
    __shared__ __align__(16) unsigned short Ks[32 * 72];      // 32 keys x (64+8)
    __shared__ __align__(16) unsigned short Vt[64 * 40];      // 64 hd  x (32+8) (transposed)
    __shared__ __align__(16) unsigned short Pw[4 * 16 * 40];  // per-wave P 16 x (32+8)
    const int t = threadIdx.x;
    const int wv = t >> 6, lane = t & 63, quad = lane >> 4, l16 = lane & 15;
    const int qt = blockIdx.x & 31;
    const int h  = (blockIdx.x >> 5) & 15;
    const int b  = blockIdx.x >> 9;
    const int qbase = qt * 64;
    const size_t bh = ((size_t)b * NH + h) * S_LEN * HD;
    const unsigned short* qg = qb + bh;
    const unsigned short* kg = kb + bh;
    const unsigned short* vg = vb + bh;

    bf16x8 qf[2];
    {
        const int qrow = qbase + wv * 16 + l16;   // A layout: m = lane&15
        qf[0] = *(const bf16x8*)&qg[qrow * HD + quad * 8];
        qf[1] = *(const bf16x8*)&qg[qrow * HD + 32 + quad * 8];
    }
    float mrow[4], lrow[4];
    floatx4 Ofr[4];
    for (int r = 0; r < 4; r++) { mrow[r] = -1e30f; lrow[r] = 0.f; }
    for (int i = 0; i < 4; i++)
        for (int r = 0; r < 4; r++) Ofr[i][r] = 0.f;

    const int ntiles = (qbase + 64) >> 5;
    const int svrow = t >> 3, svc8 = (t & 7) * 8;

    for (int kt = 0; kt < ntiles; kt++) {
        const int kbase = kt * 32;
        short8 kx = *(const short8*)&kg[(size_t)(kbase + svrow) * HD + svc8];
        short8 vx = *(const short8*)&vg[(size_t)(kbase + svrow) * HD + svc8];
        *(short8*)&Ks[svrow * 72 + svc8] = kx;
        for (int j = 0; j < 8; j++) Vt[(svc8 + j) * 40 + svrow] = (unsigned short)vx[j];
        __syncthreads();

        // scores: q(16xHD) . k^T -> 16x32 (two 16-col C frags)
        float p[2][4];
        for (int sub = 0; sub < 2; sub++) {
            floatx4 sacc;
            for (int r = 0; r < 4; r++) sacc[r] = 0.f;
            for (int hc = 0; hc < 2; hc++) {
                bf16x8 kf = *(const bf16x8*)&Ks[(sub * 16 + l16) * 72 + hc * 32 + quad * 8];
                sacc = __builtin_amdgcn_mfma_f32_16x16x32_bf16(qf[hc], kf, sacc, 0, 0, 0);
            }
            for (int r = 0; r < 4; r++) p[sub][r] = sacc[r] * 0.125f;  // 1/sqrt(64)
        }
        if (kt >= ntiles - 2) {  // only the last two tiles cross the diagonal
            for (int sub = 0; sub < 2; sub++) {
                const int key = kbase + sub * 16 + l16;
                for (int r = 0; r < 4; r++) {
                    const int qr = qbase + wv * 16 + quad * 4 + r;
                    if (key > qr) p[sub][r] = -3e38f;
                }
            }
        }
        // online softmax (row = quad*4+r; 16 lanes of a quad-group hold the 16 cols)
        for (int r = 0; r < 4; r++) {
            float mx = fmaxf(p[0][r], p[1][r]);
            for (int off = 1; off < 16; off <<= 1) mx = fmaxf(mx, __shfl_xor(mx, off, 64));
            const float mnew = fmaxf(mrow[r], mx);
            const float alpha = __expf(mrow[r] - mnew);
            p[0][r] = __expf(p[0][r] - mnew);
            p[1][r] = __expf(p[1][r] - mnew);
            float rs = p[0][r] + p[1][r];
            for (int off = 1; off < 16; off <<= 1) rs += __shfl_xor(rs, off, 64);
            lrow[r] = lrow[r] * alpha + rs;
            mrow[r] = mnew;
            for (int nt = 0; nt < 4; nt++) Ofr[nt][r] *= alpha;
        }
        // P: C-layout -> LDS -> A-layout (bf16)
        for (int sub = 0; sub < 2; sub++)
            for (int r = 0; r < 4; r++)
                Pw[wv * 640 + (quad * 4 + r) * 40 + sub * 16 + l16] = f2bf(p[sub][r]);
        __syncthreads();
        bf16x8 pf = *(const bf16x8*)&Pw[wv * 640 + l16 * 40 + quad * 8];
        for (int nt = 0; nt < 4; nt++) {
            bf16x8 vf = *(const bf16x8*)&Vt[(nt * 16 + l16) * 40 + quad * 8];
            Ofr[nt] = __builtin_amdgcn_mfma_f32_16x16x32_bf16(pf, vf, Ofr[nt], 0, 0, 0);
        }
        __syncthreads();  // protect Ks/Vt before next stage
    }

    for (int r = 0; r < 4; r++) lrow[r] = 1.f / lrow[r];
    for (int nt = 0; nt < 4; nt++) {
        for (int r = 0; r < 4; r++) {
            const int s = qbase + wv * 16 + quad * 4 + r;
            const float val = Ofr[nt][r] * lrow[r];
            // attn_out layout (B,S,H*HD): row-major k for the proj GEMM
            ao[((size_t)b * S_LEN + s) * DMODEL + h * HD + nt * 16 + l16] = f2bf(val);
        }
    }
}

// ---------------------------------------------------------------------------
// K3: out = ao @ w_proj^T + b_proj.  M=4096, N=1024, K=1024. fp32 out.
// ---------------------------------------------------------------------------
__global__ __launch_bounds__(256) void proj_kernel(
    const unsigned short* __restrict__ a, const float* __restrict__ w,
    const float* __restrict__ bias, float* __restrict__ out)
{
    __shared__ __align__(16) unsigned short As[64 * 40];
    __shared__ __align__(16) unsigned short Bs[64 * 40];
    const int t = threadIdx.x;
    const int mbase = (blockIdx.x >> 4) * 64;   // N/64 = 16
    const int nbase = (blockIdx.x & 15) * 64;
    const int wv = t >> 6, lane = t & 63, quad = lane >> 4, l16 = lane & 15;

    floatx4 acc[4];
    for (int i = 0; i < 4; i++)
        for (int r = 0; r < 4; r++) acc[i][r] = 0.f;

    const int srow = t >> 2, sc8 = (t & 3) * 8;

    for (int k0 = 0; k0 < DMODEL; k0 += 32) {
        short8 av = *(const short8*)&a[(size_t)(mbase + srow) * DMODEL + k0 + sc8];
        const float* bp = w + (size_t)(nbase + srow) * DMODEL + k0 + sc8;
        float4 b0 = *(const float4*)bp;
        float4 b1 = *(const float4*)(bp + 4);
        short8 bv;
        bv[0]=(short)f2bf(b0.x); bv[1]=(short)f2bf(b0.y); bv[2]=(short)f2bf(b0.z); bv[3]=(short)f2bf(b0.w);
        bv[4]=(short)f2bf(b1.x); bv[5]=(short)f2bf(b1.y); bv[6]=(short)f2bf(b1.z); bv[7]=(short)f2bf(b1.w);
        __syncthreads();
        *(short8*)&As[srow * 40 + sc8] = av;
        *(short8*)&Bs[srow * 40 + sc8] = bv;
        __syncthreads();
        bf16x8 af = *(const bf16x8*)&As[(wv * 16 + l16) * 40 + quad * 8];
        for (int nt = 0; nt < 4; nt++) {
            bf16x8 bf = *(const bf16x8*)&Bs[(nt * 16 + l16) * 40 + quad * 8];
            acc[nt] = __builtin_amdgcn_mfma_f32_16x16x32_bf16(af, bf, acc[nt], 0, 0, 0);
        }
    }

    for (int nt = 0; nt < 4; nt++) {
        const int n = nbase + nt * 16 + l16;
        const float bvv = bias[n];
        for (int r = 0; r < 4; r++) {
            const int m = mbase + wv * 16 + quad * 4 + r;
            out[(size_t)m * DMODEL + n] = acc[nt][r] + bvv;
        }
    }
}

extern "C" void kernel_launch(void* const* d_in, const int* in_sizes, int n_in,
                              void* d_out, int out_size, void* d_ws, size_t ws_size,
                              hipStream_t stream) {
    const float* x      = (const float*)d_in[0];
    // d_in[1] = attn_mask (causal tril) — structurally known, unused
    const float* freqs  = (const float*)d_in[2];
    const float* w_qkv  = (const float*)d_in[3];
    const float* b_qkv  = (const float*)d_in[4];
    const float* w_proj = (const float*)d_in[5];
    const float* b_proj = (const float*)d_in[6];
    float* out = (float*)d_out;

    unsigned short* ws = (unsigned short*)d_ws;
    const size_t HSZ = (size_t)2 * NH * S_LEN * HD;  // 4,194,304 elems (8 MiB bf16)
    unsigned short* qb = ws;
    unsigned short* kb = ws + HSZ;
    unsigned short* vb = ws + 2 * HSZ;
    unsigned short* ao = ws + 3 * HSZ;

    qkv_rope_kernel<<<3072, 256, 0, stream>>>(x, w_qkv, b_qkv, freqs, qb, kb, vb);
    attn_kernel<<<1024, 256, 0, stream>>>(qb, kb, vb, ao);
    proj_kernel<<<1024, 256, 0, stream>>>(ao, w_proj, b_proj, out);
}